// Round 3
// baseline (541.970 us; speedup 1.0000x reference)
//
#include <hip/hip_runtime.h>

#define T_STEPS 1024
// H = F = 6, 4H = 24 gate rows, PyTorch order: i[0:6) f[6:12) g[12:18) o[18:24)
//
// ONE batch element per wave (4096 waves = 4/SIMD). Lane = quad layout:
//   lane 4*j+g      (j=0..5, g=0..3): layer0, column j, gate g (g: 0=i,1=f,2=g,3=o)
//   lane 32+4*j+g   : layer1, column j, gate g (staggered one step: computes t-1)
//   quads 6,7 of each half duplicate column 5 (harmless, never read).
// Cross-lane is 100% VALU: gate gather = 4x v_mov_dpp quad_perm; h state is
// WAVE-UNIFORM (one element/wave) so h-broadcast = 12x v_readlane into scalar
// registers consumed directly by the next dot. ZERO DS instructions.
// Activation args are pre-folded into the weights: all rows scaled by -log2e
// (g-rows additionally x2), so sigma(x)=rcp(1+exp2(dot)) and tanh via 2*sig-1.

__device__ __forceinline__ float vexp2(float x) { return __builtin_amdgcn_exp2f(x); }
__device__ __forceinline__ float vrcp(float x)  { return __builtin_amdgcn_rcpf(x); }

// quad_perm broadcast of quad-lane PAT (0x00/0x55/0xAA/0xFF = lane 0/1/2/3)
#define DPPQ(v, PAT) \
    __int_as_float(__builtin_amdgcn_update_dpp(0, __float_as_int(v), (PAT), 0xF, 0xF, true))
#define RDL(v, LANE) \
    __int_as_float(__builtin_amdgcn_readlane(__float_as_int(v), (LANE)))

__global__ __launch_bounds__(256) void lstm2_kernel(
    const float* __restrict__ x,
    const float* __restrict__ wih0, const float* __restrict__ whh0,
    const float* __restrict__ bih0, const float* __restrict__ bhh0,
    const float* __restrict__ wih1, const float* __restrict__ whh1,
    const float* __restrict__ bih1, const float* __restrict__ bhh1,
    float* __restrict__ out, int Btot)
{
    const int tid  = threadIdx.x;
    const int lane = tid & 63;
    const int b    = blockIdx.x * 4 + (tid >> 6);   // 4 elements per 256-block
    if (b >= Btot) return;                           // uniform per wave

    const int  l    = lane & 31;
    const bool isL1 = lane >= 32;
    const int  qj   = l >> 2;
    const int  j    = (qj > 5) ? 5 : qj;             // dup quads clamp to col 5
    const int  g    = l & 3;
    const int  r    = 6 * g + j;                     // gate row in 4H

    // A-operand weights multiply h0 (recurrent h for L0, input for L1);
    // B-operand weights multiply x (L0) or h1 (L1).
    const float* wa = isL1 ? wih1 : whh0;
    const float* wb = isL1 ? whh1 : wih0;
    const float* bi = isL1 ? bih1 : bih0;
    const float* bh = isL1 ? bhh1 : bhh0;

    const float kS   = -1.44269504088896340736f * ((g == 2) ? 2.0f : 1.0f);
    const float aMul = (g == 2) ? 2.0f : 1.0f;       // tanh = 2*sig - 1 on g rows
    const float aAdd = (g == 2) ? -1.0f : 0.0f;

    float waS[6], wbS[6];
#pragma unroll
    for (int k = 0; k < 6; ++k) {
        waS[k] = wa[r * 6 + k] * kS;
        wbS[k] = wb[r * 6 + k] * kS;
    }
    const float bS = (bi[r] + bh[r]) * kS;

    float h0u[6], h1u[6];                            // wave-uniform h state
#pragma unroll
    for (int k = 0; k < 6; ++k) { h0u[k] = 0.0f; h1u[k] = 0.0f; }
    float c = 0.0f;                                  // identical across each quad

    const float* px = x   + (size_t)b * (T_STEPS * 6);
    float*       ps = out + (size_t)b * (T_STEPS * 6) + j;
    const bool lst = isL1 && (g == 0) && (qj < 6);   // lanes 32,36,..,52 store h1_j

    auto loadx = [&](int t, float v[6]) {
        const float2* p2 = reinterpret_cast<const float2*>(px + (size_t)t * 6);
        float2 a = p2[0], b2 = p2[1], c2 = p2[2];
        v[0]=a.x; v[1]=a.y; v[2]=b2.x; v[3]=b2.y; v[4]=c2.x; v[5]=c2.y;
    };

    // Iter K: L0 lanes compute step K (x(K), h0u=h0(K-1));
    //         L1 lanes compute step K-1 (input h0u=h0(K-1), recurrent h1u=h1(K-2)).
    // eX (x-dot) is off the critical chain (x prefetched 3 iters ahead).
#define ITER(K, CUR, PF)                                                      \
    {                                                                         \
        int tn_ = (K) + 3; if (tn_ > T_STEPS - 1) tn_ = T_STEPS - 1;          \
        loadx(tn_, PF);                                                       \
        float eX = 0.0f, eA = bS, eH = 0.0f;                                  \
        _Pragma("unroll")                                                     \
        for (int q = 0; q < 6; ++q) {                                         \
            eA = fmaf(waS[q], h0u[q], eA);                                    \
            eH = fmaf(wbS[q], h1u[q], eH);                                    \
            eX = fmaf(wbS[q], CUR[q], eX);                                    \
        }                                                                     \
        float e  = eA + (isL1 ? eH : eX);                                     \
        float sg = vrcp(1.0f + vexp2(e));                                     \
        float a  = fmaf(aMul, sg, aAdd);      /* sig(i/f/o) or tanh(g) */     \
        float aI = DPPQ(a, 0x00);                                             \
        float aF = DPPQ(a, 0x55);                                             \
        float aG = DPPQ(a, 0xAA);                                             \
        float aO = DPPQ(a, 0xFF);                                             \
        c = fmaf(aF, c, aI * aG);                                             \
        float th = fmaf(2.0f, vrcp(1.0f + vexp2(c * -2.88539008177792681f)),  \
                        -1.0f);                                               \
        float hv = aO * th;                                                   \
        if ((K) >= 1 && lst) ps[(size_t)((K) - 1) * 6] = hv;                  \
        h0u[0]=RDL(hv,0);  h0u[1]=RDL(hv,4);  h0u[2]=RDL(hv,8);               \
        h0u[3]=RDL(hv,12); h0u[4]=RDL(hv,16); h0u[5]=RDL(hv,20);              \
        h1u[0]=RDL(hv,32); h1u[1]=RDL(hv,36); h1u[2]=RDL(hv,40);              \
        h1u[3]=RDL(hv,44); h1u[4]=RDL(hv,48); h1u[5]=RDL(hv,52);              \
    }

    float xA[6], xB[6], xC[6], xD[6];
    loadx(0, xA); loadx(1, xB); loadx(2, xC);

    // Peel K=0: L0 computes real step 0; L1 lanes compute garbage (bias-driven),
    // so reset their state after.
    ITER(0, xA, xD);
    if (isL1) c = 0.0f;
#pragma unroll
    for (int k = 0; k < 6; ++k) h1u[k] = 0.0f;

    // Main: K = 1..1024 (256 exact quads). At K = T the L0 lanes compute a garbage
    // step T (clamped x) whose output is never consumed; L1 produces row T-1.
    for (int k = 1; k <= T_STEPS; k += 4) {
        ITER(k,     xB, xA);
        ITER(k + 1, xC, xB);
        ITER(k + 2, xD, xC);
        ITER(k + 3, xA, xD);
    }
#undef ITER
}

extern "C" void kernel_launch(void* const* d_in, const int* in_sizes, int n_in,
                              void* d_out, int out_size, void* d_ws, size_t ws_size,
                              hipStream_t stream)
{
    const float* x    = (const float*)d_in[0];
    const float* wih0 = (const float*)d_in[1];
    const float* whh0 = (const float*)d_in[2];
    const float* bih0 = (const float*)d_in[3];
    const float* bhh0 = (const float*)d_in[4];
    const float* wih1 = (const float*)d_in[5];
    const float* whh1 = (const float*)d_in[6];
    const float* bih1 = (const float*)d_in[7];
    const float* bhh1 = (const float*)d_in[8];
    float* out = (float*)d_out;

    const int Btot   = in_sizes[0] / (T_STEPS * 6);
    const int blocks = (Btot + 3) / 4;     // 4 elements (waves) per 256-thread block
    hipLaunchKernelGGL(lstm2_kernel, dim3(blocks), dim3(256), 0, stream,
                       x, wih0, whh0, bih0, bhh0, wih1, whh1, bih1, bhh1, out, Btot);
}

// Round 4
// 404.534 us; speedup vs baseline: 1.3397x; 1.3397x over previous
//
#include <hip/hip_runtime.h>

#define T_STEPS 1024
// H = F = 6, 4H = 24 rows, PyTorch gate order: i[0:6) f[6:12) g[12:18) o[18:24)
//
// R1's issue-optimal mapping (16 lanes/element, 4 elements/wave, 1 wave/SIMD),
// with ALL cross-lane traffic moved from the DS pipe to VALU DPP:
//   - partner gate exchange lane^1  -> v_mov_b32_dpp quad_perm [1,0,3,2]
//   - h broadcast from even lanes   -> v_mov_b32_dpp row_newbcast:{0,2,..,10}
//     (16-lane group == one DPP row, so row_newbcast is exactly the broadcast)
// Activation exp2 scales (-log2e; -2log2e for g rows) are pre-folded into the
// weights/biases; p0-dependent activation fixup is a single FMA with per-lane
// constants. x is prefetched 3 iterations ahead through 4 rotating buffers.
// ZERO DS instructions remain.

__device__ __forceinline__ float vexp2(float x) { return __builtin_amdgcn_exp2f(x); }
__device__ __forceinline__ float vrcp(float x)  { return __builtin_amdgcn_rcpf(x); }

// quad_perm [1,0,3,2]: partner exchange lane^1 (VALU)
#define DPP_XOR1(v) \
    __int_as_float(__builtin_amdgcn_update_dpp(0, __float_as_int(v), 0x0B1, 0xF, 0xF, true))
// row_newbcast:N (gfx90a+): all lanes of each 16-lane row get lane N of that row
#define ROWBC(v, N) \
    __int_as_float(__builtin_amdgcn_update_dpp(0, __float_as_int(v), 0x150 + (N), 0xF, 0xF, true))

// One LSTM step for this lane's two gate rows.
// p0 (even) lanes: rows (i_j, g_j), own c_j/h_j.  p1 lanes: rows (f_j, o_j).
// Weights pre-scaled so sigma(x) = rcp(1 + exp2(dot)).
__device__ __forceinline__ float lstm_step(
    const float in[6], float hs[6], float& c,
    const float wiA[6], const float whA[6], float bA,
    const float wiB[6], const float whB[6], float bB,
    float aM, float aC)
{
    float sA = bA, tA = 0.0f, sB = bB, tB = 0.0f;
#pragma unroll
    for (int k = 0; k < 6; ++k) {
        sA = fmaf(wiA[k], in[k], sA);
        tA = fmaf(whA[k], hs[k], tA);
        sB = fmaf(wiB[k], in[k], sB);
        tB = fmaf(whB[k], hs[k], tB);
    }
    float a0 = vrcp(1.0f + vexp2(sA + tA));        // sig(i) (p0) | sig(f) (p1)
    float sb = vrcp(1.0f + vexp2(sB + tB));
    float a1 = fmaf(aM, sb, aC);                   // tanh(g) (p0) | sig(o) (p1)

    float af = DPP_XOR1(a0);                       // on p0: sig(f) from partner
    float ao = DPP_XOR1(a1);                       // on p0: sig(o) from partner

    c = fmaf(af, c, a0 * a1);                      // valid on even lanes
    float th = fmaf(2.0f, vrcp(1.0f + vexp2(c * -2.88539008177792681f)), -1.0f);
    float hv = ao * th;                            // valid on even lanes

    hs[0] = ROWBC(hv, 0);  hs[1] = ROWBC(hv, 2);  hs[2] = ROWBC(hv, 4);
    hs[3] = ROWBC(hv, 6);  hs[4] = ROWBC(hv, 8);  hs[5] = ROWBC(hv, 10);
    return hv;
}

__global__ __launch_bounds__(256) void lstm2_kernel(
    const float* __restrict__ x,
    const float* __restrict__ wih0, const float* __restrict__ whh0,
    const float* __restrict__ bih0, const float* __restrict__ bhh0,
    const float* __restrict__ wih1, const float* __restrict__ whh1,
    const float* __restrict__ bih1, const float* __restrict__ bhh1,
    float* __restrict__ out, int Btot)
{
    const int tid = threadIdx.x;
    const int grp = tid >> 4;            // 16 elements per 256-thread block
    const int l   = tid & 15;
    const int b   = blockIdx.x * 16 + grp;
    if (b >= Btot) return;               // uniform per group

    const int p0 = ((l & 1) == 0) ? 1 : 0;
    int j = l >> 1; if (j > 5) j = 5;    // lanes 12..15 duplicate j=5 (unused)
    const int rA = p0 ? j      : 6 + j;  // i_j | f_j
    const int rB = p0 ? 12 + j : 18 + j; // g_j | o_j

    const float kA = -1.44269504088896340736f;            // -log2e
    const float kB = p0 ? -2.88539008177792681f : kA;     // g rows: -2log2e
    const float aM = p0 ? 2.0f : 1.0f;                    // tanh = 2*sig - 1
    const float aC = p0 ? -1.0f : 0.0f;

    float wiA0[6], whA0[6], wiB0[6], whB0[6];
    float wiA1[6], whA1[6], wiB1[6], whB1[6];
#pragma unroll
    for (int k = 0; k < 6; ++k) {
        wiA0[k] = wih0[rA * 6 + k] * kA; whA0[k] = whh0[rA * 6 + k] * kA;
        wiB0[k] = wih0[rB * 6 + k] * kB; whB0[k] = whh0[rB * 6 + k] * kB;
        wiA1[k] = wih1[rA * 6 + k] * kA; whA1[k] = whh1[rA * 6 + k] * kA;
        wiB1[k] = wih1[rB * 6 + k] * kB; whB1[k] = whh1[rB * 6 + k] * kB;
    }
    const float bA0 = (bih0[rA] + bhh0[rA]) * kA;
    const float bB0 = (bih0[rB] + bhh0[rB]) * kB;
    const float bA1 = (bih1[rA] + bhh1[rA]) * kA;
    const float bB1 = (bih1[rB] + bhh1[rB]) * kB;

    float h0s[6], h1s[6];
#pragma unroll
    for (int k = 0; k < 6; ++k) { h0s[k] = 0.0f; h1s[k] = 0.0f; }
    float c0 = 0.0f, c1 = 0.0f;

    const float* px   = x   + (size_t)b * (T_STEPS * 6);
    float*       pout = out + (size_t)b * (T_STEPS * 6);
    const bool lst = p0 && (l < 12);

    auto loadx = [&](int t, float v[6]) {
        const float2* p2 = reinterpret_cast<const float2*>(px + (size_t)t * 6);
        float2 a = p2[0], b2 = p2[1], c2 = p2[2];
        v[0]=a.x; v[1]=a.y; v[2]=b2.x; v[3]=b2.y; v[4]=c2.x; v[5]=c2.y;
    };

    // Iter K: layer1 computes step K-1 (input h0s = h0(K-1), recurrent h1(K-2)),
    // then layer0 computes step K (x(K), h0(K-1)) -> independent chains, the
    // scheduler interleaves them. x(K+3) prefetched into the freed buffer.
#define ITER(K, CUR, PF)                                                       \
    {                                                                          \
        int tn_ = (K) + 3; if (tn_ > T_STEPS - 1) tn_ = T_STEPS - 1;           \
        loadx(tn_, PF);                                                        \
        float hv1 = lstm_step(h0s, h1s, c1, wiA1, whA1, bA1,                   \
                              wiB1, whB1, bB1, aM, aC);                        \
        lstm_step(CUR, h0s, c0, wiA0, whA0, bA0, wiB0, whB0, bB0, aM, aC);     \
        if ((K) >= 1 && lst) pout[(size_t)((K) - 1) * 6 + j] = hv1;            \
    }

    float xA[6], xB[6], xC[6], xD[6];
    loadx(0, xA); loadx(1, xB); loadx(2, xC); loadx(3, xD);

    // Peel K=0: layer0 only (h1/c1 stay zero until their first real step at K=1).
    lstm_step(xA, h0s, c0, wiA0, whA0, bA0, wiB0, whB0, bB0, aM, aC);

    // Main: K = 1..1024 (256 exact quads). At K = 1024 layer0 runs a garbage
    // step (clamped x) whose output is never consumed; layer1 emits row 1023.
    for (int k = 1; k <= T_STEPS; k += 4) {
        ITER(k,     xB, xA);
        ITER(k + 1, xC, xB);
        ITER(k + 2, xD, xC);
        ITER(k + 3, xA, xD);
    }
#undef ITER
}

extern "C" void kernel_launch(void* const* d_in, const int* in_sizes, int n_in,
                              void* d_out, int out_size, void* d_ws, size_t ws_size,
                              hipStream_t stream)
{
    const float* x    = (const float*)d_in[0];
    const float* wih0 = (const float*)d_in[1];
    const float* whh0 = (const float*)d_in[2];
    const float* bih0 = (const float*)d_in[3];
    const float* bhh0 = (const float*)d_in[4];
    const float* wih1 = (const float*)d_in[5];
    const float* whh1 = (const float*)d_in[6];
    const float* bih1 = (const float*)d_in[7];
    const float* bhh1 = (const float*)d_in[8];
    float* out = (float*)d_out;

    const int Btot   = in_sizes[0] / (T_STEPS * 6);
    const int blocks = (Btot + 15) / 16;   // 16 elements per 256-thread block
    hipLaunchKernelGGL(lstm2_kernel, dim3(blocks), dim3(256), 0, stream,
                       x, wih0, whh0, bih0, bhh0, wih1, whh1, bih1, bhh1, out, Btot);
}